// Round 2
// baseline (1651.341 us; speedup 1.0000x reference)
//
#include <hip/hip_runtime.h>
#include <hip/hip_bf16.h>

// TreeHopNode: h = q - rep + (per-head MLP(sigmoid(Qh*Kh/16)*Vh)) @ Ws
// N=65536, E=1024, H=4, G=256, MLP=256. All GEMMs in bf16 MFMA, f32 accum.
//
// R2 changes vs R1:
//  - qkvz: LDS stash -> packed-bf16 register stash (kills ~8-way scalar LDS
//    conflicts, halves LDS 64->32KB, occupancy 2->3 blocks/CU)
//  - all MFMA tiles: XOR-swizzled LDS layout via pre-swizzled global source
//    (global_load_lds writes linearly; source granule (l&7)^((l>>3)&7), read
//    XORs the same involution) -> frag ds_read_b128 16-way -> 2-way (free).

#define BM 128
#define BN 128
#define BK 64

typedef __attribute__((ext_vector_type(8))) short bf16x8;
typedef __attribute__((ext_vector_type(4))) float f32x4;
typedef __attribute__((ext_vector_type(4))) short short4v;

static __device__ __forceinline__ short f2b(float x) {
  __hip_bfloat16 h = __float2bfloat16(x);
  return __builtin_bit_cast(short, h);
}
static __device__ __forceinline__ float b2f(short s) {
  unsigned u = ((unsigned)(unsigned short)s) << 16;
  return __builtin_bit_cast(float, u);
}

// ---- async global->LDS staging of a [128 rows x 64 k] bf16 tile ----
// LDS receives linear lane order: lane l -> byte r0*128 + l*16
// (row r0 + l/8, 16B-granule l&7). We pre-swizzle the SOURCE so that LDS
// granule gi of row r holds global granule gi ^ (r&7)  (involution).
static __device__ __forceinline__ void stage_tile(
    const short* __restrict__ g, int ld, short* lds, int wave, int lane)
{
  const int gr = (lane & 7) ^ ((lane >> 3) & 7);   // swizzled source granule
  const short* gl = g + (long)(lane >> 3) * ld + (gr << 3);
  #pragma unroll
  for (int i = 0; i < 4; ++i) {
    const int r0 = (wave * 4 + i) * 8;   // 8 rows per instruction, 4 insts/wave
    __builtin_amdgcn_global_load_lds(
        (const __attribute__((address_space(1))) void*)(gl + (long)r0 * ld),
        (__attribute__((address_space(3))) void*)(lds + r0 * BK),
        16, 0, 0);
  }
}

// MFMA 16x16x32 fragment: lane l -> row r0+(l&15), k = kk + (l>>4)*8 .. +8.
// Apply the same XOR involution on the 16B granule index.
static __device__ __forceinline__ bf16x8 frag(const short* lds, int r0, int kk, int lane) {
  const int row = r0 + (lane & 15);
  const int g0 = (kk >> 3) + (lane >> 4);
  return *(const bf16x8*)(lds + row * BK + (((g0 ^ row) & 7) << 3));
}

// ---------------- convert f32 -> bf16, vectorized ----------------
__global__ void cvt_bf16(const float* __restrict__ in, short* __restrict__ out, long n) {
  long i = ((long)blockIdx.x * blockDim.x + threadIdx.x) * 4;
  const long stride = (long)gridDim.x * blockDim.x * 4;
  for (; i < n; i += stride) {
    float4 v = *(const float4*)(in + i);
    short4v o = { f2b(v.x), f2b(v.y), f2b(v.z), f2b(v.w) };
    *(short4v*)(out + i) = o;
  }
}

// ---------------- transpose + convert weights ----------------
__global__ void prep_weights(
    const float* __restrict__ Wq, const float* __restrict__ Wk, const float* __restrict__ Wv,
    const float* __restrict__ W1, const float* __restrict__ W2, const float* __restrict__ Ws,
    short* __restrict__ wqt, short* __restrict__ wkt, short* __restrict__ wvt,
    short* __restrict__ w1t, short* __restrict__ w2t, short* __restrict__ wst)
{
  const int job = blockIdx.z;
  const float* src; short* dst; int R, C;
  if (job < 3)       { src = (job==0)?Wq:((job==1)?Wk:Wv); dst = (job==0)?wqt:((job==1)?wkt:wvt); R = 1024; C = 1024; }
  else if (job == 3) { src = Ws; dst = wst; R = 1024; C = 1024; }
  else if (job < 8)  { int h = job-4; src = W1 + h*65536; dst = w1t + h*65536; R = 256; C = 256; }
  else               { int h = job-8; src = W2 + h*65536; dst = w2t + h*65536; R = 256; C = 256; }
  const int c0 = blockIdx.x * 32, r0 = blockIdx.y * 32;
  if (c0 >= C || r0 >= R) return;
  __shared__ float t[32][33];
  for (int i = threadIdx.y; i < 32; i += 8)
    t[i][threadIdx.x] = src[(long)(r0 + i) * C + c0 + threadIdx.x];
  __syncthreads();
  for (int i = threadIdx.y; i < 32; i += 8)
    dst[(long)(c0 + i) * R + r0 + threadIdx.x] = f2b(t[threadIdx.x][i]);
}

// ---------------- fused QKV + sigmoid gate -> z ----------------
// 3 sequential K=1024 passes per 128x128 tile; Qh then gate kept in packed
// bf16 REGISTERS (acc lane->elem mapping identical across passes).
__global__ __launch_bounds__(256) void qkvz_kernel(
    const short* __restrict__ qb, const short* __restrict__ rb,
    const short* __restrict__ wqt, const short* __restrict__ wkt, const short* __restrict__ wvt,
    short* __restrict__ z)
{
  __shared__ __align__(16) short lA[BM * BK];
  __shared__ __align__(16) short lB[BN * BK];
  const int lane = threadIdx.x & 63, wave = threadIdx.x >> 6;
  const int wm = wave >> 1, wn = wave & 1;
  const long bm = (long)blockIdx.y * BM;
  const int  bn = blockIdx.x * BN;

  short4v stash[4][4];   // packed bf16: Qh after pass0, gate after pass1

  for (int pass = 0; pass < 3; ++pass) {
    const short* A  = ((pass == 0) ? qb : rb) + bm * 1024;
    const short* Bt = ((pass == 0) ? wqt : ((pass == 1) ? wkt : wvt)) + (long)bn * 1024;
    f32x4 acc[4][4] = {};
    for (int k0 = 0; k0 < 1024; k0 += BK) {
      __syncthreads();                       // prior readers of lA/lB done
      stage_tile(A  + k0, 1024, lA, wave, lane);
      stage_tile(Bt + k0, 1024, lB, wave, lane);
      __syncthreads();                       // vmcnt(0) drain -> tiles ready
      #pragma unroll
      for (int kk = 0; kk < BK; kk += 32) {
        bf16x8 af[4], bg[4];
        #pragma unroll
        for (int i = 0; i < 4; ++i) af[i] = frag(lA, wm * 64 + i * 16, kk, lane);
        #pragma unroll
        for (int j = 0; j < 4; ++j) bg[j] = frag(lB, wn * 64 + j * 16, kk, lane);
        #pragma unroll
        for (int i = 0; i < 4; ++i)
          #pragma unroll
          for (int j = 0; j < 4; ++j)
            acc[i][j] = __builtin_amdgcn_mfma_f32_16x16x32_bf16(af[i], bg[j], acc[i][j], 0, 0, 0);
      }
    }
    // epilogue, all in registers; C/D layout: col=lane&15, row=(lane>>4)*4+reg
    if (pass == 0) {
      #pragma unroll
      for (int i = 0; i < 4; ++i)
        #pragma unroll
        for (int j = 0; j < 4; ++j) {
          short4v s;
          #pragma unroll
          for (int r = 0; r < 4; ++r) s[r] = f2b(acc[i][j][r]);
          stash[i][j] = s;
        }
    } else if (pass == 1) {
      #pragma unroll
      for (int i = 0; i < 4; ++i)
        #pragma unroll
        for (int j = 0; j < 4; ++j) {
          short4v s;
          #pragma unroll
          for (int r = 0; r < 4; ++r) {
            const float x = b2f(stash[i][j][r]) * acc[i][j][r] * 0.0625f;
            s[r] = f2b(1.0f / (1.0f + __expf(-x)));
          }
          stash[i][j] = s;
        }
    } else {
      #pragma unroll
      for (int i = 0; i < 4; ++i)
        #pragma unroll
        for (int j = 0; j < 4; ++j)
          #pragma unroll
          for (int r = 0; r < 4; ++r) {
            const int rl = wm * 64 + i * 16 + ((lane >> 4) << 2) + r;
            const int cl = wn * 64 + j * 16 + (lane & 15);
            z[(bm + rl) * 1024 + bn + cl] = f2b(b2f(stash[i][j][r]) * acc[i][j][r]);
          }
    }
  }
}

// ---------------- generic 128x128-tile bf16 GEMM ----------------
template <int KDIM, bool RELU, bool BIAS, bool RESID>
__global__ __launch_bounds__(256) void gemm_bf16(
    const short* __restrict__ A, long lda, long zsa,
    const short* __restrict__ Bt, long ldb, long zsb,
    void* __restrict__ outv, long ldc, long zsc,
    const float* __restrict__ bias, long zsbias,
    const float* __restrict__ q, const float* __restrict__ rep)
{
  __shared__ __align__(16) short lA[BM * BK];
  __shared__ __align__(16) short lB[BN * BK];
  const int lane = threadIdx.x & 63, wave = threadIdx.x >> 6;
  const int wm = wave >> 1, wn = wave & 1;
  const long bm = (long)blockIdx.y * BM;
  const int  bn = blockIdx.x * BN;
  const int  zi = blockIdx.z;

  const short* Ab = A + (long)zi * zsa + bm * lda;
  const short* Bb = Bt + (long)zi * zsb + (long)bn * ldb;
  f32x4 acc[4][4] = {};
  for (int k0 = 0; k0 < KDIM; k0 += BK) {
    __syncthreads();
    stage_tile(Ab + k0, (int)lda, lA, wave, lane);
    stage_tile(Bb + k0, (int)ldb, lB, wave, lane);
    __syncthreads();
    #pragma unroll
    for (int kk = 0; kk < BK; kk += 32) {
      bf16x8 af[4], bg[4];
      #pragma unroll
      for (int i = 0; i < 4; ++i) af[i] = frag(lA, wm * 64 + i * 16, kk, lane);
      #pragma unroll
      for (int j = 0; j < 4; ++j) bg[j] = frag(lB, wn * 64 + j * 16, kk, lane);
      #pragma unroll
      for (int i = 0; i < 4; ++i)
        #pragma unroll
        for (int j = 0; j < 4; ++j)
          acc[i][j] = __builtin_amdgcn_mfma_f32_16x16x32_bf16(af[i], bg[j], acc[i][j], 0, 0, 0);
    }
  }
  #pragma unroll
  for (int i = 0; i < 4; ++i)
    #pragma unroll
    for (int j = 0; j < 4; ++j)
      #pragma unroll
      for (int r = 0; r < 4; ++r) {
        const int rl = wm * 64 + i * 16 + ((lane >> 4) << 2) + r;
        const int cl = wn * 64 + j * 16 + (lane & 15);
        float v = acc[i][j][r];
        if (BIAS) v += bias[(long)zi * zsbias + bn + cl];
        if (RELU) v = v > 0.0f ? v : 0.0f;
        const long row = bm + rl;
        if (RESID) {
          const long gi = row * ldc + bn + cl;   // ldc == 1024, full width
          ((float*)outv)[gi] = q[gi] - rep[gi] + v;
        } else {
          ((short*)outv)[(long)zi * zsc + row * ldc + bn + cl] = f2b(v);
        }
      }
}

extern "C" void kernel_launch(void* const* d_in, const int* in_sizes, int n_in,
                              void* d_out, int out_size, void* d_ws, size_t ws_size,
                              hipStream_t stream) {
  const float* q   = (const float*)d_in[0];
  const float* rep = (const float*)d_in[1];
  const float* Wq  = (const float*)d_in[2];
  const float* Wk  = (const float*)d_in[3];
  const float* Wv  = (const float*)d_in[4];
  const float* W1  = (const float*)d_in[5];
  const float* b1  = (const float*)d_in[6];
  const float* W2  = (const float*)d_in[7];
  const float* b2  = (const float*)d_in[8];
  const float* Ws  = (const float*)d_in[9];
  float* out = (float*)d_out;

  const long NE = 67108864L;   // 65536 * 1024
  char* ws = (char*)d_ws;
  short* qb  = (short*)(ws);                 // q bf16    (128 MiB)
  short* rb  = (short*)(ws + NE * 2);        // rep bf16  (128 MiB)
  short* zb  = (short*)(ws + NE * 4);        // z bf16    (128 MiB)
  char*  wp  = ws + NE * 6;
  short* wqt = (short*)(wp);                 // 2 MiB each
  short* wkt = (short*)(wp + 2097152);
  short* wvt = (short*)(wp + 4194304);
  short* wst = (short*)(wp + 6291456);
  short* w1t = (short*)(wp + 8388608);       // 512 KiB
  short* w2t = (short*)(wp + 8912896);       // 512 KiB
  short* h1b = qb;   // reuse: q bf16 dead after qkvz
  short* ugb = rb;   // reuse: rep bf16 dead after qkvz

  cvt_bf16<<<4096, 256, 0, stream>>>(q,   qb, NE);
  cvt_bf16<<<4096, 256, 0, stream>>>(rep, rb, NE);
  prep_weights<<<dim3(32, 32, 12), dim3(32, 8), 0, stream>>>(
      Wq, Wk, Wv, W1, W2, Ws, wqt, wkt, wvt, w1t, w2t, wst);

  qkvz_kernel<<<dim3(8, 512), 256, 0, stream>>>(qb, rb, wqt, wkt, wvt, zb);

  // h1 = relu(z @ W1 + b1), per head (head = blockIdx.z)
  gemm_bf16<256, true, true, false><<<dim3(2, 512, 4), 256, 0, stream>>>(
      zb, 1024, 256, w1t, 256, 65536, h1b, 1024, 256, b1, 256, nullptr, nullptr);
  // ug = h1 @ W2 + b2, per head
  gemm_bf16<256, false, true, false><<<dim3(2, 512, 4), 256, 0, stream>>>(
      h1b, 1024, 256, w2t, 256, 65536, ugb, 1024, 256, b2, 256, nullptr, nullptr);
  // out = q - rep + ug @ Ws
  gemm_bf16<1024, false, false, true><<<dim3(8, 512, 1), 256, 0, stream>>>(
      ugb, 1024, 0, wst, 1024, 0, out, 1024, 0, nullptr, 0, q, rep);
}

// Round 3
// 1297.934 us; speedup vs baseline: 1.2723x; 1.2723x over previous
//
#include <hip/hip_runtime.h>
#include <hip/hip_bf16.h>

// TreeHopNode: h = q - rep + (per-head MLP(sigmoid(Qh*Kh/16)*Vh)) @ Ws
// N=65536, E=1024, H=4, G=256, MLP=256. All GEMMs in bf16 MFMA, f32 accum.
//
// R3 changes vs R2:
//  - qkvz stash kernel REMOVED (R1: 8-way LDS conflicts; R2: VGPR 216 ->
//    occupancy 12%). Replaced by 3 chained plain GEMMs with streaming
//    epilogues: G1 Qh -> gh; G2 gate=sigmoid(Qh*Kh/16) in-place on gh;
//    G3 z=gate*Vh. Extra ~512 MiB traffic hides under compute-bound GEMMs.
//  - kept XOR-swizzled LDS (R2: conflicts -> 0)
//  - XCD-chunk block swizzle on the 4 big GEMMs (A-panel locality per-XCD L2)

#define BM 128
#define BN 128
#define BK 64

typedef __attribute__((ext_vector_type(8))) short bf16x8;
typedef __attribute__((ext_vector_type(4))) float f32x4;
typedef __attribute__((ext_vector_type(4))) short short4v;

static __device__ __forceinline__ short f2b(float x) {
  __hip_bfloat16 h = __float2bfloat16(x);
  return __builtin_bit_cast(short, h);
}
static __device__ __forceinline__ float b2f(short s) {
  unsigned u = ((unsigned)(unsigned short)s) << 16;
  return __builtin_bit_cast(float, u);
}

// ---- async global->LDS staging of a [128 rows x 64 k] bf16 tile ----
// global_load_lds writes LDS linearly (base + lane*16B): lane l -> row
// r0 + l/8, granule l&7. Source granule is pre-swizzled (l&7)^(row&7), so
// LDS granule gi of row r holds global granule gi ^ (r&7)  (involution).
static __device__ __forceinline__ void stage_tile(
    const short* __restrict__ g, int ld, short* lds, int wave, int lane)
{
  const int gr = (lane & 7) ^ ((lane >> 3) & 7);   // swizzled source granule
  const short* gl = g + (long)(lane >> 3) * ld + (gr << 3);
  #pragma unroll
  for (int i = 0; i < 4; ++i) {
    const int r0 = (wave * 4 + i) * 8;   // 8 rows per instruction, 4 insts/wave
    __builtin_amdgcn_global_load_lds(
        (const __attribute__((address_space(1))) void*)(gl + (long)r0 * ld),
        (__attribute__((address_space(3))) void*)(lds + r0 * BK),
        16, 0, 0);
  }
}

// MFMA 16x16x32 fragment: lane l -> row r0+(l&15), k = kk + (l>>4)*8 .. +8.
// Read back through the same XOR involution -> 2-way banks (free, m136).
static __device__ __forceinline__ bf16x8 frag(const short* lds, int r0, int kk, int lane) {
  const int row = r0 + (lane & 15);
  const int g0 = (kk >> 3) + (lane >> 4);
  return *(const bf16x8*)(lds + row * BK + (((g0 ^ row) & 7) << 3));
}

// ---------------- convert f32 -> bf16, vectorized ----------------
__global__ void cvt_bf16(const float* __restrict__ in, short* __restrict__ out, long n) {
  long i = ((long)blockIdx.x * blockDim.x + threadIdx.x) * 4;
  const long stride = (long)gridDim.x * blockDim.x * 4;
  for (; i < n; i += stride) {
    float4 v = *(const float4*)(in + i);
    short4v o = { f2b(v.x), f2b(v.y), f2b(v.z), f2b(v.w) };
    *(short4v*)(out + i) = o;
  }
}

// ---------------- transpose + convert weights ----------------
__global__ void prep_weights(
    const float* __restrict__ Wq, const float* __restrict__ Wk, const float* __restrict__ Wv,
    const float* __restrict__ W1, const float* __restrict__ W2, const float* __restrict__ Ws,
    short* __restrict__ wqt, short* __restrict__ wkt, short* __restrict__ wvt,
    short* __restrict__ w1t, short* __restrict__ w2t, short* __restrict__ wst)
{
  const int job = blockIdx.z;
  const float* src; short* dst; int R, C;
  if (job < 3)       { src = (job==0)?Wq:((job==1)?Wk:Wv); dst = (job==0)?wqt:((job==1)?wkt:wvt); R = 1024; C = 1024; }
  else if (job == 3) { src = Ws; dst = wst; R = 1024; C = 1024; }
  else if (job < 8)  { int h = job-4; src = W1 + h*65536; dst = w1t + h*65536; R = 256; C = 256; }
  else               { int h = job-8; src = W2 + h*65536; dst = w2t + h*65536; R = 256; C = 256; }
  const int c0 = blockIdx.x * 32, r0 = blockIdx.y * 32;
  if (c0 >= C || r0 >= R) return;
  __shared__ float t[32][33];
  for (int i = threadIdx.y; i < 32; i += 8)
    t[i][threadIdx.x] = src[(long)(r0 + i) * C + c0 + threadIdx.x];
  __syncthreads();
  for (int i = threadIdx.y; i < 32; i += 8)
    dst[(long)(c0 + i) * R + r0 + threadIdx.x] = f2b(t[threadIdx.x][i]);
}

// ---------------- generic 128x128-tile bf16 GEMM ----------------
// C = ep(A @ Bt^T); Bt stored [col][k]. blockIdx.z batches heads via element
// strides zsa/zsb/zsc/zsbias.
// GATE==1: out = sigmoid(b2f(eg[gi]) * acc / 16)   (eg may alias out)
// GATE==2: out = b2f(eg[gi]) * acc
// RESID:   f32 out = q - rep + acc (full-width, ldc==1024)
// SWZ:     XCD-chunk block swizzle (requires gridDim.x==8, nwg%8==0)
template <int KDIM, int GATE, bool RELU, bool BIAS, bool RESID, bool SWZ>
__global__ __launch_bounds__(256) void gemm_bf16(
    const short* __restrict__ A, long lda, long zsa,
    const short* __restrict__ Bt, long ldb, long zsb,
    void* __restrict__ outv, long ldc, long zsc,
    const float* __restrict__ bias, long zsbias,
    const short* __restrict__ eg,
    const float* __restrict__ q, const float* __restrict__ rep)
{
  __shared__ __align__(16) short lA[BM * BK];
  __shared__ __align__(16) short lB[BN * BK];
  const int lane = threadIdx.x & 63, wave = threadIdx.x >> 6;
  const int wm = wave >> 1, wn = wave & 1;
  int bx = blockIdx.x, by = blockIdx.y;
  if (SWZ) {
    // consecutive dispatch ids -> same XCD chunk covers contiguous A-panels
    const int flat = by * 8 + bx;
    const int chunk = (int)(gridDim.x * gridDim.y) >> 3;
    const int fid = (flat & 7) * chunk + (flat >> 3);
    bx = fid & 7; by = fid >> 3;
  }
  const long bm = (long)by * BM;
  const int  bn = bx * BN;
  const int  zi = blockIdx.z;

  const short* Ab = A + (long)zi * zsa + bm * lda;
  const short* Bb = Bt + (long)zi * zsb + (long)bn * ldb;
  f32x4 acc[4][4] = {};
  for (int k0 = 0; k0 < KDIM; k0 += BK) {
    __syncthreads();
    stage_tile(Ab + k0, (int)lda, lA, wave, lane);
    stage_tile(Bb + k0, (int)ldb, lB, wave, lane);
    __syncthreads();
    #pragma unroll
    for (int kk = 0; kk < BK; kk += 32) {
      bf16x8 af[4], bg[4];
      #pragma unroll
      for (int i = 0; i < 4; ++i) af[i] = frag(lA, wm * 64 + i * 16, kk, lane);
      #pragma unroll
      for (int j = 0; j < 4; ++j) bg[j] = frag(lB, wn * 64 + j * 16, kk, lane);
      #pragma unroll
      for (int i = 0; i < 4; ++i)
        #pragma unroll
        for (int j = 0; j < 4; ++j)
          acc[i][j] = __builtin_amdgcn_mfma_f32_16x16x32_bf16(af[i], bg[j], acc[i][j], 0, 0, 0);
    }
  }
  // epilogue; C/D layout: col=lane&15, row=(lane>>4)*4+reg (m89)
  #pragma unroll
  for (int i = 0; i < 4; ++i)
    #pragma unroll
    for (int j = 0; j < 4; ++j)
      #pragma unroll
      for (int r = 0; r < 4; ++r) {
        const int rl = wm * 64 + i * 16 + ((lane >> 4) << 2) + r;
        const int cl = wn * 64 + j * 16 + (lane & 15);
        float v = acc[i][j][r];
        if (BIAS) v += bias[(long)zi * zsbias + bn + cl];
        if (RELU) v = v > 0.0f ? v : 0.0f;
        const long row = bm + rl;
        const long gi = (long)zi * zsc + row * ldc + bn + cl;
        if (GATE == 1) {
          const float x = b2f(eg[gi]) * v * 0.0625f;   // Qh*Kh/sqrt(256)
          v = 1.0f / (1.0f + __expf(-x));
        } else if (GATE == 2) {
          v = b2f(eg[gi]) * v;                          // gate*Vh
        }
        if (RESID) {
          ((float*)outv)[gi] = q[gi] - rep[gi] + v;
        } else {
          ((short*)outv)[gi] = f2b(v);
        }
      }
}

extern "C" void kernel_launch(void* const* d_in, const int* in_sizes, int n_in,
                              void* d_out, int out_size, void* d_ws, size_t ws_size,
                              hipStream_t stream) {
  const float* q   = (const float*)d_in[0];
  const float* rep = (const float*)d_in[1];
  const float* Wq  = (const float*)d_in[2];
  const float* Wk  = (const float*)d_in[3];
  const float* Wv  = (const float*)d_in[4];
  const float* W1  = (const float*)d_in[5];
  const float* b1  = (const float*)d_in[6];
  const float* W2  = (const float*)d_in[7];
  const float* b2  = (const float*)d_in[8];
  const float* Ws  = (const float*)d_in[9];
  float* out = (float*)d_out;

  const long NE = 67108864L;   // 65536 * 1024
  char* ws = (char*)d_ws;
  // 3 x 128 MiB slots; max 3 buffers live at any point:
  //   slotA: qb (cvt..G1)      -> zb (G3..M1)
  //   slotB: rb (cvt..G3)      -> ug (M2..F)
  //   slotC: gh (G1..G3)       -> h1 (M1..M2)
  short* qb  = (short*)(ws);
  short* rb  = (short*)(ws + NE * 2);
  short* gh  = (short*)(ws + NE * 4);
  short* zb  = qb;
  short* ugb = rb;
  short* h1b = gh;
  char*  wp  = ws + NE * 6;
  short* wqt = (short*)(wp);                 // 2 MiB each
  short* wkt = (short*)(wp + 2097152);
  short* wvt = (short*)(wp + 4194304);
  short* wst = (short*)(wp + 6291456);
  short* w1t = (short*)(wp + 8388608);       // 512 KiB
  short* w2t = (short*)(wp + 8912896);       // 512 KiB

  cvt_bf16<<<4096, 256, 0, stream>>>(q,   qb, NE);
  cvt_bf16<<<4096, 256, 0, stream>>>(rep, rb, NE);
  prep_weights<<<dim3(32, 32, 12), dim3(32, 8), 0, stream>>>(
      Wq, Wk, Wv, W1, W2, Ws, wqt, wkt, wvt, w1t, w2t, wst);

  // G1: Qh = q @ Wq  (bf16 -> gh)
  gemm_bf16<1024, 0, false, false, false, true><<<dim3(8, 512), 256, 0, stream>>>(
      qb, 1024, 0, wqt, 1024, 0, gh, 1024, 0, nullptr, 0, nullptr, nullptr, nullptr);
  // G2: gate = sigmoid(Qh * (rep @ Wk) / 16)  (in-place over gh)
  gemm_bf16<1024, 1, false, false, false, true><<<dim3(8, 512), 256, 0, stream>>>(
      rb, 1024, 0, wkt, 1024, 0, gh, 1024, 0, nullptr, 0, gh, nullptr, nullptr);
  // G3: z = gate * (rep @ Wv)  -> zb
  gemm_bf16<1024, 2, false, false, false, true><<<dim3(8, 512), 256, 0, stream>>>(
      rb, 1024, 0, wvt, 1024, 0, zb, 1024, 0, nullptr, 0, gh, nullptr, nullptr);

  // M1: h1 = relu(z @ W1 + b1), per head (head = blockIdx.z)
  gemm_bf16<256, 0, true, true, false, false><<<dim3(2, 512, 4), 256, 0, stream>>>(
      zb, 1024, 256, w1t, 256, 65536, h1b, 1024, 256, b1, 256, nullptr, nullptr, nullptr);
  // M2: ug = h1 @ W2 + b2, per head
  gemm_bf16<256, 0, false, true, false, false><<<dim3(2, 512, 4), 256, 0, stream>>>(
      h1b, 1024, 256, w2t, 256, 65536, ugb, 1024, 256, b2, 256, nullptr, nullptr, nullptr);
  // F: out = q - rep + ug @ Ws  (f32 epilogue)
  gemm_bf16<1024, 0, false, false, true, true><<<dim3(8, 512), 256, 0, stream>>>(
      ugb, 1024, 0, wst, 1024, 0, out, 1024, 0, nullptr, 0, nullptr, q, rep);
}